// Round 9
// baseline (627.430 us; speedup 1.0000x reference)
//
#include <hip/hip_runtime.h>

#define NNODES 50000
#define NEDGES 500000
#define NBINS  (NNODES * 4)
#define NSCANB 196   // ceil(NBINS / 1024)
#define MPAD   50176 // 1568*32

// wf fp32 arena offsets (in floats)
#define WF_W1    0
#define WF_B1    4096
#define WF_W2    4160
#define WF_B2    8256
#define WF_W3    8320
#define WF_B3    8384
#define WF_SSC   8385
#define WF_STC   9409
#define WF_BIAS  10433
#define WF_GAMMA 10689
#define WF_BETA  10945
#define WF_TOT   11201

typedef __attribute__((ext_vector_type(8))) short short8;
typedef __attribute__((ext_vector_type(4))) short short4v;
typedef __attribute__((ext_vector_type(4))) float floatx4;
typedef __attribute__((ext_vector_type(4))) unsigned int uint4v;

__device__ __forceinline__ float bf2f(unsigned short u) {
    return __uint_as_float(((unsigned)u) << 16);
}
__device__ __forceinline__ unsigned f2bf(float f) {
    unsigned u = __float_as_uint(f);
    u += 0x7fffu + ((u >> 16) & 1u);
    return u >> 16;
}
__device__ __forceinline__ float bflo(unsigned u) { return __uint_as_float(u << 16); }
__device__ __forceinline__ float bfhi(unsigned u) { return __uint_as_float(u & 0xffff0000u); }
__device__ __forceinline__ int clampi(int v, int hi) { return v < 0 ? 0 : (v > hi ? hi : v); }

__device__ __forceinline__ short8 pack_bf16(const float* p) {
    short8 r;
#pragma unroll
    for (int j = 0; j < 8; j++) r[j] = (short)f2bf(p[j]);
    return r;
}

// ---------------------------------------------------------------------------
// dtype probe: flag=1 means inputs are fp32
// ---------------------------------------------------------------------------
__global__ __launch_bounds__(256) void probe_k(const unsigned short* __restrict__ xs,
                                               unsigned* __restrict__ flag) {
    __shared__ unsigned cnt;
    if (threadIdx.x == 0) cnt = 0;
    __syncthreads();
    unsigned local = 0;
    for (int i = threadIdx.x; i < 8192; i += 256) {
        float v = bf2f(xs[i]);
        if (!(fabsf(v) < 1e10f)) local++;
    }
    atomicAdd(&cnt, local);
    __syncthreads();
    if (threadIdx.x == 0) *flag = (cnt > 256u) ? 1u : 0u;
}

// ---------------------------------------------------------------------------
// polymorphic small-param conversion into fp32 arena
// ---------------------------------------------------------------------------
__device__ __forceinline__ float ldf(const void* p, int i, bool f32) {
    return f32 ? ((const float*)p)[i] : bf2f(((const unsigned short*)p)[i]);
}

__global__ __launch_bounds__(1024) void wconv_k(const void* W1, const void* b1,
                                                const void* W2, const void* b2,
                                                const void* W3, const void* b3,
                                                const void* ssc, const void* stc,
                                                const void* bias, const void* gamma,
                                                const void* beta,
                                                const unsigned* __restrict__ flag,
                                                float* __restrict__ wf) {
    bool f32 = (*flag != 0u);
    for (int i = threadIdx.x; i < WF_TOT; i += 1024) {
        float v;
        if (i < WF_B1)          v = ldf(W1, i - WF_W1, f32);
        else if (i < WF_W2)     v = ldf(b1, i - WF_B1, f32);
        else if (i < WF_B2)     v = ldf(W2, i - WF_W2, f32);
        else if (i < WF_W3)     v = ldf(b2, i - WF_B2, f32);
        else if (i < WF_B3)     v = ldf(W3, i - WF_W3, f32);
        else if (i < WF_SSC)    v = ldf(b3, i - WF_B3, f32);
        else if (i < WF_STC)    v = ldf(ssc, i - WF_SSC, f32);
        else if (i < WF_BIAS)   v = ldf(stc, i - WF_STC, f32);
        else if (i < WF_GAMMA)  v = ldf(bias, i - WF_BIAS, f32);
        else if (i < WF_BETA)   v = ldf(gamma, i - WF_GAMMA, f32);
        else                    v = ldf(beta, i - WF_BETA, f32);
        wf[i] = v;
    }
}

// ---------------------------------------------------------------------------
// bulk matrix conversion (fp32|bf16 -> bf16), zero-padded to npad elems
// ---------------------------------------------------------------------------
__global__ __launch_bounds__(256) void convbf_k(const void* __restrict__ src,
                                                unsigned short* __restrict__ dst,
                                                int nelem, int npad,
                                                const unsigned* __restrict__ flag) {
    int i8 = (blockIdx.x * 256 + threadIdx.x) * 8;
    if (i8 >= npad) return;
    short8 o;
    if (i8 < nelem) {
        if (*flag) {
            const float* pf = (const float*)src + i8;
            floatx4 a = *(const floatx4*)pf;
            floatx4 b = *(const floatx4*)(pf + 4);
            o[0] = (short)f2bf(a[0]); o[1] = (short)f2bf(a[1]);
            o[2] = (short)f2bf(a[2]); o[3] = (short)f2bf(a[3]);
            o[4] = (short)f2bf(b[0]); o[5] = (short)f2bf(b[1]);
            o[6] = (short)f2bf(b[2]); o[7] = (short)f2bf(b[3]);
        } else {
            o = *(const short8*)((const unsigned short*)src + i8);
        }
    } else {
#pragma unroll
        for (int j = 0; j < 8; j++) o[j] = 0;
    }
    *(short8*)(dst + i8) = o;
}

// ---------------------------------------------------------------------------
// fused one-pass GEMM: one wave per (32 rows of x) x (10 of 20 column groups).
// cg<16: proj columns (writes proj (n,r,h,f) + fused s_src/s_trg dots);
// cg>=16: skip columns (writes d_out).
// ---------------------------------------------------------------------------
__global__ __launch_bounds__(64) void gemm_fused_k(const unsigned short* __restrict__ A,
                                                   const unsigned short* __restrict__ Bp,
                                                   const unsigned short* __restrict__ Bs,
                                                   unsigned short* __restrict__ proj,
                                                   unsigned short* __restrict__ out16,
                                                   float* __restrict__ out32,
                                                   const float* __restrict__ wf,
                                                   float* __restrict__ s_src,
                                                   float* __restrict__ s_trg,
                                                   const unsigned* __restrict__ flag) {
    const bool cf32 = (*flag != 0u);
    const int lane = threadIdx.x & 63;
    const int l15 = lane & 15, q = lane >> 4;
    const int m0 = blockIdx.x * 32;
    const int cg0 = blockIdx.y * 10;

    // A-stripe: 32 rows x 256 K in registers (64 VGPRs)
    short8 af[2][8];
#pragma unroll
    for (int mt = 0; mt < 2; mt++)
#pragma unroll
        for (int ks = 0; ks < 8; ks++)
            af[mt][ks] = *(const short8*)(A + (size_t)(m0 + mt * 16 + l15) * 256 + ks * 32 + q * 8);

#pragma unroll 1
    for (int cgi = 0; cgi < 10; cgi++) {
        const int cg = cg0 + cgi;
        const bool isproj = (cg < 16);
        const unsigned short* Bb = isproj ? (Bp + (size_t)(cg * 64) * 256)
                                          : (Bs + (size_t)((cg - 16) * 64) * 256);
        floatx4 acc[2][4];
#pragma unroll
        for (int i = 0; i < 2; i++)
#pragma unroll
            for (int j = 0; j < 4; j++) acc[i][j] = (floatx4){0.f, 0.f, 0.f, 0.f};
#pragma unroll
        for (int ks = 0; ks < 8; ks++) {
            short8 bfr[4];
#pragma unroll
            for (int nt = 0; nt < 4; nt++)
                bfr[nt] = *(const short8*)(Bb + (size_t)(nt * 16 + l15) * 256 + ks * 32 + q * 8);
#pragma unroll
            for (int mt = 0; mt < 2; mt++)
#pragma unroll
                for (int nt = 0; nt < 4; nt++)
                    acc[mt][nt] = __builtin_amdgcn_mfma_f32_16x16x32_bf16(af[mt][ks], bfr[nt],
                                                                         acc[mt][nt], 0, 0, 0);
        }

        if (isproj) {
            const int h = cg >> 2, r = cg & 3;
            const int colbase = (r * 4 + h) * 64;   // (r,h,f) layout
            const int cell = h * 4 + r;
            float sa[4], sb[4];
#pragma unroll
            for (int nt = 0; nt < 4; nt++) {
                sa[nt] = wf[WF_SSC + cell * 64 + nt * 16 + l15];
                sb[nt] = wf[WF_STC + cell * 64 + nt * 16 + l15];
            }
#pragma unroll
            for (int mt = 0; mt < 2; mt++) {
                float pa[4] = {0.f, 0.f, 0.f, 0.f};
                float pb[4] = {0.f, 0.f, 0.f, 0.f};
#pragma unroll
                for (int nt = 0; nt < 4; nt++)
#pragma unroll
                    for (int rg = 0; rg < 4; rg++) {
                        int row = m0 + mt * 16 + q * 4 + rg;
                        float v = acc[mt][nt][rg];
                        unsigned short vb = (unsigned short)f2bf(v);
                        if (row < NNODES)
                            proj[(size_t)row * 1024 + colbase + nt * 16 + l15] = vb;
                        float vr = bf2f(vb);   // match bf16-rounded score path
                        pa[rg] = fmaf(vr, sa[nt], pa[rg]);
                        pb[rg] = fmaf(vr, sb[nt], pb[rg]);
                    }
#pragma unroll
                for (int off = 1; off < 16; off <<= 1)
#pragma unroll
                    for (int rg = 0; rg < 4; rg++) {
                        pa[rg] += __shfl_xor(pa[rg], off);
                        pb[rg] += __shfl_xor(pb[rg], off);
                    }
                if (l15 == 0) {
#pragma unroll
                    for (int rg = 0; rg < 4; rg++) {
                        int row = m0 + mt * 16 + q * 4 + rg;
                        if (row < NNODES) {
                            s_src[row * 16 + cell] = pa[rg];
                            s_trg[row * 16 + cell] = pb[rg];
                        }
                    }
                }
            }
        } else {
            const int cb = (cg - 16) * 64;
#pragma unroll
            for (int mt = 0; mt < 2; mt++)
#pragma unroll
                for (int nt = 0; nt < 4; nt++)
#pragma unroll
                    for (int rg = 0; rg < 4; rg++) {
                        int row = m0 + mt * 16 + q * 4 + rg;
                        if (row < NNODES) {
                            size_t idx = (size_t)row * 256 + cb + nt * 16 + l15;
                            float v = acc[mt][nt][rg];
                            if (cf32) out32[idx] = v;
                            else      out16[idx] = (unsigned short)f2bf(v);
                        }
                    }
        }
    }
}

// ---------------------------------------------------------------------------
// CSR build: count -> hierarchical scan -> fill
// ---------------------------------------------------------------------------
__global__ __launch_bounds__(256) void count_k(const int* __restrict__ trg,
                                               const int* __restrict__ rel,
                                               unsigned* __restrict__ counts, int E) {
    int e = blockIdx.x * 256 + threadIdx.x;
    if (e >= E) return;
    int g = clampi(trg[e], NNODES - 1);
    int r = clampi(rel[e], 3);
    atomicAdd(&counts[g * 4 + r], 1u);
}

__global__ __launch_bounds__(256) void scan1_k(const unsigned* __restrict__ counts,
                                               unsigned* __restrict__ offsets,
                                               unsigned* __restrict__ bsum) {
    __shared__ unsigned ts[256];
    int t = threadIdx.x;
    int base = blockIdx.x * 1024 + t * 4;
    uint4v c = {0u, 0u, 0u, 0u};
    if (base + 3 < NBINS) c = *(const uint4v*)(counts + base);
    else {
#pragma unroll
        for (int j = 0; j < 4; j++) c[j] = (base + j < NBINS) ? counts[base + j] : 0u;
    }
    ts[t] = c[0] + c[1] + c[2] + c[3];
    __syncthreads();
    for (int off = 1; off < 256; off <<= 1) {
        unsigned v = (t >= off) ? ts[t - off] : 0u;
        __syncthreads();
        ts[t] += v;
        __syncthreads();
    }
    unsigned pre = (t == 0) ? 0u : ts[t - 1];
    uint4v o;
    o[0] = pre;
    o[1] = pre + c[0];
    o[2] = pre + c[0] + c[1];
    o[3] = pre + c[0] + c[1] + c[2];
    if (base + 3 < NBINS) *(uint4v*)(offsets + base) = o;
    else {
#pragma unroll
        for (int j = 0; j < 4; j++) if (base + j < NBINS) offsets[base + j] = o[j];
    }
    if (t == 255) bsum[blockIdx.x] = ts[255];
}

__global__ __launch_bounds__(256) void scan2_k(unsigned* __restrict__ bsum,
                                               unsigned* __restrict__ offsets) {
    __shared__ unsigned ts[256];
    int t = threadIdx.x;
    unsigned v = (t < NSCANB) ? bsum[t] : 0u;
    ts[t] = v;
    __syncthreads();
    for (int off = 1; off < 256; off <<= 1) {
        unsigned u = (t >= off) ? ts[t - off] : 0u;
        __syncthreads();
        ts[t] += u;
        __syncthreads();
    }
    if (t < NSCANB) bsum[t] = (t == 0) ? 0u : ts[t - 1];
    if (t == 255) offsets[NBINS] = ts[255];
}

__global__ __launch_bounds__(256) void scan3_k(unsigned* __restrict__ offsets,
                                               unsigned* __restrict__ cursor,
                                               const unsigned* __restrict__ bsum) {
    int t = threadIdx.x;
    unsigned base = bsum[blockIdx.x];
    int idx = blockIdx.x * 1024 + t * 4;
    if (idx + 3 < NBINS) {
        uint4v o = *(const uint4v*)(offsets + idx);
        o[0] += base; o[1] += base; o[2] += base; o[3] += base;
        *(uint4v*)(offsets + idx) = o;
        *(uint4v*)(cursor + idx) = o;
    } else {
#pragma unroll
        for (int j = 0; j < 4; j++)
            if (idx + j < NBINS) {
                unsigned v = offsets[idx + j] + base;
                offsets[idx + j] = v;
                cursor[idx + j] = v;
            }
    }
}

__global__ __launch_bounds__(256) void fill_k(const int* __restrict__ src,
                                              const int* __restrict__ trg,
                                              const int* __restrict__ rel,
                                              const float* __restrict__ s_src,
                                              const float* __restrict__ s_trg,
                                              unsigned* __restrict__ cursor,
                                              unsigned* __restrict__ esrc,
                                              floatx4* __restrict__ eexp, int E) {
    int e = blockIdx.x * 256 + threadIdx.x;
    if (e >= E) return;
    int s = clampi(src[e], NNODES - 1);
    int g = clampi(trg[e], NNODES - 1);
    int r = clampi(rel[e], 3);
    unsigned pos = atomicAdd(&cursor[g * 4 + r], 1u);
    if (pos >= (unsigned)E) pos = E - 1;
    esrc[pos] = (unsigned)s;
    floatx4 v;
#pragma unroll
    for (int h = 0; h < 4; h++) {
        float val = s_src[s * 16 + h * 4 + r] + s_trg[g * 16 + h * 4 + r];
        val = val > 0.f ? val : 0.2f * val;
        v[h] = expf(val);
    }
    eexp[pos] = v;
}

// ---------------------------------------------------------------------------
// aggregation: one WAVE per bin (n,r). proj (n, r, h, f): per edge ONE
// contiguous 512B wave load. agg layout (bin, h, f) bf16.
// ---------------------------------------------------------------------------
__global__ __launch_bounds__(256) void rowagg2_k(const unsigned* __restrict__ offsets,
                                                 const unsigned* __restrict__ esrc,
                                                 const floatx4* __restrict__ eexp,
                                                 const unsigned short* __restrict__ proj,
                                                 unsigned short* __restrict__ agg) {
    int wave = threadIdx.x >> 6, lane = threadIdx.x & 63;
    int bin = blockIdx.x * 4 + wave;
    if (bin >= NBINS) return;
    int r = bin & 3;
    int h = lane >> 4;
    unsigned beg = offsets[bin], end = offsets[bin + 1];

    float a0 = 0.f, a1 = 0.f, a2 = 0.f, a3 = 0.f, den = 0.f;
    for (unsigned i = beg; i < end; i++) {
        unsigned s = esrc[i];
        floatx4 pe = eexp[i];
        float p = pe[h];
        const short4v* pp = (const short4v*)(proj + (size_t)s * 1024 + r * 256) + lane;
        short4v v = *pp;
        den += p;
        a0 = fmaf(p, bf2f((unsigned short)v[0]), a0);
        a1 = fmaf(p, bf2f((unsigned short)v[1]), a1);
        a2 = fmaf(p, bf2f((unsigned short)v[2]), a2);
        a3 = fmaf(p, bf2f((unsigned short)v[3]), a3);
    }
    float inv = 1.f / (den + 1e-16f);
    short4v o;
    o[0] = (short)f2bf(a0 * inv);
    o[1] = (short)f2bf(a1 * inv);
    o[2] = (short)f2bf(a2 * inv);
    o[3] = (short)f2bf(a3 * inv);
    *((short4v*)(agg + (size_t)bin * 256) + lane) = o;
}

// ---------------------------------------------------------------------------
// MFMA MLP
// ---------------------------------------------------------------------------
__global__ __launch_bounds__(256, 2) void mlp_mfma_k(const unsigned short* __restrict__ agg,
                                                     const float* __restrict__ wf,
                                                     float* __restrict__ sc) {
    __shared__ float lds[4][16 * 68];
    const int wave = threadIdx.x >> 6;
    const int lane = threadIdx.x & 63;
    const int l15 = lane & 15, q = lane >> 4;
    float* L = lds[wave];

    short8 w1f[2][4], w2f[2][4];
#pragma unroll
    for (int ks = 0; ks < 2; ks++)
#pragma unroll
        for (int nt = 0; nt < 4; nt++) {
            w1f[ks][nt] = pack_bf16(wf + WF_W1 + (nt * 16 + l15) * 64 + ks * 32 + q * 8);
            w2f[ks][nt] = pack_bf16(wf + WF_W2 + (nt * 16 + l15) * 64 + ks * 32 + q * 8);
        }
    float b1v[4], b2v[4], w3v[4];
#pragma unroll
    for (int nt = 0; nt < 4; nt++) {
        b1v[nt] = wf[WF_B1 + nt * 16 + l15];
        b2v[nt] = wf[WF_B2 + nt * 16 + l15];
        w3v[nt] = wf[WF_W3 + nt * 16 + l15];
    }
    float b3v = wf[WF_B3];

    int wave_id = blockIdx.x * 4 + wave;
#pragma unroll 1
    for (int t = 0; t < 4; t++) {
        int row0 = (wave_id * 4 + t) * 16;
        short8 a1[2];
#pragma unroll
        for (int ks = 0; ks < 2; ks++)
            a1[ks] = *(const short8*)(agg + (size_t)(row0 + l15) * 64 + ks * 32 + q * 8);
        floatx4 acc1[4];
#pragma unroll
        for (int nt = 0; nt < 4; nt++) {
            acc1[nt] = (floatx4){0.f, 0.f, 0.f, 0.f};
            acc1[nt] = __builtin_amdgcn_mfma_f32_16x16x32_bf16(a1[0], w1f[0][nt], acc1[nt], 0, 0, 0);
            acc1[nt] = __builtin_amdgcn_mfma_f32_16x16x32_bf16(a1[1], w1f[1][nt], acc1[nt], 0, 0, 0);
        }
        __syncthreads();
#pragma unroll
        for (int nt = 0; nt < 4; nt++)
#pragma unroll
            for (int rg = 0; rg < 4; rg++)
                L[(q * 4 + rg) * 68 + nt * 16 + l15] = fmaxf(acc1[nt][rg] + b1v[nt], 0.f);
        __syncthreads();
        short8 a2[2];
#pragma unroll
        for (int ks = 0; ks < 2; ks++) {
            short8 rr;
#pragma unroll
            for (int j = 0; j < 8; j++)
                rr[j] = (short)f2bf(L[l15 * 68 + ks * 32 + q * 8 + j]);
            a2[ks] = rr;
        }
        floatx4 acc2[4];
#pragma unroll
        for (int nt = 0; nt < 4; nt++) {
            acc2[nt] = (floatx4){0.f, 0.f, 0.f, 0.f};
            acc2[nt] = __builtin_amdgcn_mfma_f32_16x16x32_bf16(a2[0], w2f[0][nt], acc2[nt], 0, 0, 0);
            acc2[nt] = __builtin_amdgcn_mfma_f32_16x16x32_bf16(a2[1], w2f[1][nt], acc2[nt], 0, 0, 0);
        }
        float p[4];
#pragma unroll
        for (int rg = 0; rg < 4; rg++) {
            float s = 0.f;
#pragma unroll
            for (int nt = 0; nt < 4; nt++)
                s = fmaf(fmaxf(acc2[nt][rg] + b2v[nt], 0.f), w3v[nt], s);
            p[rg] = s;
        }
#pragma unroll
        for (int off = 1; off < 16; off <<= 1) {
#pragma unroll
            for (int rg = 0; rg < 4; rg++) p[rg] += __shfl_xor(p[rg], off);
        }
        if (l15 == 0) {
#pragma unroll
            for (int rg = 0; rg < 4; rg++) {
                float acc = p[rg] + b3v;
                float sp = fmaxf(acc, 0.f) + log1pf(expf(-fabsf(acc)));
                float m = acc * tanhf(sp);
                int s_id = row0 + q * 4 + rg;
                int n = s_id >> 4, r = (s_id >> 2) & 3, h = s_id & 3;
                sc[n * 16 + h * 4 + r] = m;
            }
        }
    }
}

// ---------------------------------------------------------------------------
// final: softmax over r, weighted sum, +skip(in d_out)+bias, ELU, LayerNorm
// ---------------------------------------------------------------------------
__global__ __launch_bounds__(256) void final_k(const unsigned short* __restrict__ agg,
                                               const float* __restrict__ sc,
                                               const float* __restrict__ wf,
                                               const unsigned* __restrict__ flag,
                                               unsigned short* __restrict__ out16,
                                               float* __restrict__ out32) {
    const bool f32 = (*flag != 0u);
    int n = blockIdx.x, t = threadIdx.x;
    int h = t >> 6, f = t & 63;
    float s0 = sc[n * 16 + h * 4 + 0];
    float s1 = sc[n * 16 + h * 4 + 1];
    float s2 = sc[n * 16 + h * 4 + 2];
    float s3 = sc[n * 16 + h * 4 + 3];
    float mx = fmaxf(fmaxf(s0, s1), fmaxf(s2, s3));
    float e0 = expf(s0 - mx), e1 = expf(s1 - mx), e2 = expf(s2 - mx), e3 = expf(s3 - mx);
    float inv = 1.f / (e0 + e1 + e2 + e3);
    size_t base = (size_t)n * 1024 + h * 64 + f;
    float a0 = bf2f(agg[base]);
    float a1 = bf2f(agg[base + 256]);
    float a2 = bf2f(agg[base + 512]);
    float a3 = bf2f(agg[base + 768]);
    float v = (e0 * a0 + e1 * a1 + e2 * a2 + e3 * a3) * inv;
    size_t oidx = (size_t)n * 256 + t;
    float skipv = f32 ? out32[oidx] : bf2f(out16[oidx]);
    v += skipv + wf[WF_BIAS + t];
    v = v > 0.f ? v : expm1f(v);

    float s = v, qq = v * v;
#pragma unroll
    for (int o = 1; o < 64; o <<= 1) {
        s += __shfl_xor(s, o);
        qq += __shfl_xor(qq, o);
    }
    __shared__ float red[8];
    __shared__ float stat[2];
    int wv = t >> 6, ln = t & 63;
    if (ln == 0) { red[wv] = s; red[4 + wv] = qq; }
    __syncthreads();
    if (t == 0) {
        float S = red[0] + red[1] + red[2] + red[3];
        float Q = red[4] + red[5] + red[6] + red[7];
        float mu = S * (1.f / 256.f);
        float var = fmaxf(Q * (1.f / 256.f) - mu * mu, 0.f);
        stat[0] = mu;
        stat[1] = rsqrtf(var + 1e-5f);
    }
    __syncthreads();
    float o = (v - stat[0]) * stat[1] * wf[WF_GAMMA + t] + wf[WF_BETA + t];
    if (f32) out32[oidx] = o;
    else     out16[oidx] = (unsigned short)f2bf(o);
}

// ---------------------------------------------------------------------------
// workspace layout (~226.85 MB). Overlays (serial-stream disjoint lifetimes):
//   xbf  -> agg region     (xbf read only by gemm_fused; agg written later)
//   wpbf/wsbf -> eexp head (weights read by gemm_fused; eexp written by fill_k)
// ---------------------------------------------------------------------------
extern "C" void kernel_launch(void* const* d_in, const int* in_sizes, int n_in,
                              void* d_out, int out_size, void* d_ws, size_t ws_size,
                              hipStream_t stream) {
    if (ws_size < 226900000) return;

    const void* x      = d_in[0];
    const int* src     = (const int*)d_in[1];
    const int* trg     = (const int*)d_in[2];
    const int* rel     = (const int*)d_in[3];
    const void* W_proj = d_in[5];
    const void* ssc    = d_in[6];
    const void* stc    = d_in[7];
    const void* W1     = d_in[8];
    const void* b1     = d_in[9];
    const void* W2     = d_in[10];
    const void* b2     = d_in[11];
    const void* W3     = d_in[12];
    const void* b3     = d_in[13];
    const void* W_skip = d_in[14];
    const void* bias   = d_in[15];
    const void* gamma  = d_in[16];
    const void* beta   = d_in[17];
    unsigned short* out16 = (unsigned short*)d_out;
    float* out32          = (float*)d_out;

    char* w = (char*)d_ws;
    unsigned short* proj = (unsigned short*)(w + 0);
    unsigned short* agg  = (unsigned short*)(w + 102400000);
    unsigned short* xbf  = (unsigned short*)(w + 102400000);  // overlay agg
    float* s_src         = (float*)(w + 204800000);
    float* s_trg         = (float*)(w + 208000000);
    floatx4* eexp        = (floatx4*)(w + 211200000);
    unsigned short* wpbf = (unsigned short*)(w + 211200000);  // overlay eexp head
    unsigned short* wsbf = (unsigned short*)(w + 212300000);  // overlay eexp head
    unsigned* esrc       = (unsigned*)(w + 219200000);
    unsigned* counts     = (unsigned*)(w + 221200000);
    unsigned* offsets    = (unsigned*)(w + 222000000);
    unsigned* cursor     = (unsigned*)(w + 222800016);
    float* sc            = (float*)(w + 223600016);
    float* wf            = (float*)(w + 226800016);
    unsigned* flag       = (unsigned*)(w + 226844824);
    unsigned* bsum       = (unsigned*)(w + 226844832);

    hipMemsetAsync(counts, 0, NBINS * 4, stream);

    probe_k<<<1, 256, 0, stream>>>((const unsigned short*)x, flag);
    wconv_k<<<1, 1024, 0, stream>>>(W1, b1, W2, b2, W3, b3, ssc, stc, bias, gamma, beta,
                                    flag, wf);
    convbf_k<<<(MPAD * 256) / (8 * 256), 256, 0, stream>>>(x, xbf, NNODES * 256,
                                                           MPAD * 256, flag);
    convbf_k<<<128, 256, 0, stream>>>(W_proj, wpbf, 1024 * 256, 1024 * 256, flag);
    convbf_k<<<32, 256, 0, stream>>>(W_skip, wsbf, 256 * 256, 256 * 256, flag);
    // proj + skip + score dots, one pass over A per column half
    gemm_fused_k<<<dim3(1568, 2), 64, 0, stream>>>(xbf, wpbf, wsbf, proj, out16, out32,
                                                   wf, s_src, s_trg, flag);
    count_k<<<1954, 256, 0, stream>>>(trg, rel, counts, NEDGES);
    scan1_k<<<NSCANB, 256, 0, stream>>>(counts, offsets, bsum);
    scan2_k<<<1, 256, 0, stream>>>(bsum, offsets);
    scan3_k<<<NSCANB, 256, 0, stream>>>(offsets, cursor, bsum);
    fill_k<<<1954, 256, 0, stream>>>(src, trg, rel, s_src, s_trg, cursor, esrc, eexp, NEDGES);
    rowagg2_k<<<NBINS / 4, 256, 0, stream>>>(offsets, esrc, eexp, proj, agg);
    mlp_mfma_k<<<3125, 256, 0, stream>>>(agg, wf, sc);
    final_k<<<NNODES, 256, 0, stream>>>(agg, sc, wf, flag, out16, out32);
}